// Round 4
// baseline (309.781 us; speedup 1.0000x reference)
//
#include <hip/hip_runtime.h>
#include <math.h>

// Problem constants
#define TT 8
#define BB 128
#define GG 256
#define DD 64
#define NCH 4     // D chunks
#define CF4 4     // float4s per cell per chunk (16 floats)
#define ST 4      // LDS stride in float4s (16 dwords: 2-way bank alias = free, m136)
#define NPAIR ((TT - 1) * BB)

// ws layout: [0..15] floats reserved (u32 counter at [0], memset to 0 by host side)
//            partials at ws+16: part[pair*8 + j], j: 0 zdiff, 1 pres, 2 poolc(neg),
//            3 obj, 4 flow_sq, 5 sum(zp), 6 sum(flow)

__device__ inline float wred(float v) {
#pragma unroll
    for (int off = 32; off > 0; off >>= 1) v += __shfl_xor(v, off, 64);
    return v;
}
__device__ inline float dot4(float4 a, float4 b) {
    return a.x * b.x + a.y * b.y + a.z * b.z + a.w * b.w;
}
__device__ inline float4 fabs4(float4 a) {
    return make_float4(fabsf(a.x), fabsf(a.y), fabsf(a.z), fabsf(a.w));
}
__device__ inline float4 max4(float4 a, float4 b) {
    return make_float4(fmaxf(a.x, b.x), fmaxf(a.y, b.y), fmaxf(a.z, b.z), fmaxf(a.w, b.w));
}
__device__ inline float4 scale4(float4 a, float s) {
    return make_float4(a.x * s, a.y * s, a.z * s, a.w * s);
}
__device__ inline float4 sub4(float4 a, float4 b) {
    return make_float4(a.x - b.x, a.y - b.y, a.z - b.z, a.w - b.w);
}
__device__ inline float4 shfl4(float4 v, int src) {
    return make_float4(__shfl(v.x, src, 64), __shfl(v.y, src, 64),
                       __shfl(v.z, src, 64), __shfl(v.w, src, 64));
}

__global__ __launch_bounds__(256, 4) void pair_kernel(const float* __restrict__ zw,
                                                      const float* __restrict__ zp,
                                                      const float* __restrict__ flow,
                                                      float* __restrict__ wsbase,
                                                      const int* __restrict__ gs,
                                                      float* __restrict__ out) {
    const int pairIdx = blockIdx.x;            // 0 .. 7*BB-1
    const int t = pairIdx >> 7;                // BB = 128
    const int b = pairIdx & (BB - 1);
    const int tid = threadIdx.x;
    const int gi = tid >> 4, gj = tid & 15;
    const int lane = tid & 63;

    __shared__ float4 shR[GG * ST];            // row-max of wa (pool intermediate)
    __shared__ float4 shB[GG * ST];            // raw B chunk
    __shared__ float pA[GG], pB[GG], nB[GG];
    __shared__ float bred[8][4];
    __shared__ int isLast;

    float* part = wsbase + 16;

    const float4* gA = (const float4*)zw + (size_t)(t * BB + b) * 1024;
    const float4* gB = gA + (size_t)BB * 1024;

    const float pAc = zp[(size_t)(t * BB + b) * GG + tid];
    const float pBc = zp[(size_t)((t + 1) * BB + b) * GG + tid];
    pA[tid] = pAc;
    pB[tid] = pBc;

    // 9 wrapped neighbors (jnp.roll semantics) + in-bounds bitmask (clamped ops)
    int nbc[9];
    unsigned inbM = 0;
    {
        int m = 0;
#pragma unroll
        for (int di = -1; di <= 1; di++) {
#pragma unroll
            for (int dj = -1; dj <= 1; dj++) {
                nbc[m] = (((gi + di) & 15) << 4) | ((gj + dj) & 15);
                if (((unsigned)(gi + di) < 16u) && ((unsigned)(gj + dj) < 16u))
                    inbM |= (1u << m);
                m++;
            }
        }
    }
    __syncthreads();

    float zdiff = 0.f, sa = 0.f, sb = 0.f, poolDot = 0.f, poolN = 0.f;
    float dots[9] = {0.f, 0.f, 0.f, 0.f, 0.f, 0.f, 0.f, 0.f, 0.f};

    // unroll 1: full unroll hoists all chunks' global loads and spills
    // (round-2 post-mortem: VGPR=256, 293 MB scratch traffic)
#pragma unroll 1
    for (int c = 0; c < NCH; c++) {
        float4 aA[CF4], aB[CF4];
#pragma unroll
        for (int q = 0; q < CF4; q++) {
            aA[q] = gA[tid * 16 + c * 4 + q];
            aB[q] = gB[tid * 16 + c * 4 + q];
        }
        // register-local terms + row-max via intra-wave shuffle (gj+-1 never
        // crosses the 64-lane wave: rows of 16, clamped at row edges)
#pragma unroll
        for (int q = 0; q < CF4; q++) {
            float4 d = sub4(aB[q], aA[q]);
            zdiff += dot4(d, d);
            sa += dot4(aA[q], aA[q]);
            sb += dot4(aB[q], aB[q]);
            dots[4] += dot4(aA[q], aB[q]);          // center dot from registers
            float4 wa = scale4(fabs4(aA[q]), pAc);
            float4 rm = wa;
            float4 lft = shfl4(wa, lane - 1);
            if (gj > 0) rm = max4(rm, lft);
            float4 rgt = shfl4(wa, lane + 1);
            if (gj < 15) rm = max4(rm, rgt);
            shB[tid * ST + q] = aB[q];
            shR[tid * ST + q] = rm;
        }
        __syncthreads();

        // neighbor dots: A(center, regs) . B(neighbor, LDS)
#pragma unroll
        for (int k = 0; k < 9; k++) {
            if (k == 4) continue;
            int base = nbc[k] * ST;
#pragma unroll
            for (int q = 0; q < CF4; q++) dots[k] += dot4(aA[q], shB[base + q]);
        }

        // pool: clamped col-max of row-max, then accumulate dot/norm
#pragma unroll
        for (int q = 0; q < CF4; q++) {
            float4 sm = shR[tid * ST + q];
            if (gi > 0) sm = max4(sm, shR[(tid - 16) * ST + q]);
            if (gi < 15) sm = max4(sm, shR[(tid + 16) * ST + q]);
            poolDot += dot4(sm, fabs4(aB[q]));
            poolN += dot4(sm, sm);
        }
        __syncthreads();   // before next chunk overwrites shR/shB
    }

    // ---- epilogues ----
    nB[tid] = sqrtf(sb);
    __syncthreads();

    // objects
    float prior_n = fmaxf(sqrtf(sa), 1e-8f);
    float sum_sim = 0.f, max_sim = -1e30f;
    bool has = false;
#pragma unroll
    for (int k = 0; k < 9; k++) {
        float nn = fmaxf(nB[nbc[k]], 1e-8f);
        float s = dots[k] / (prior_n * nn);
        if (pB[nbc[k]] > 0.5f) {
            sum_sim += s;
            max_sim = fmaxf(max_sim, s);
            has = true;
        }
    }
    float obj = ((pAc > 0.5f) && has) ? (sum_sim - 5.0f * max_sim) : 0.f;

    // pool
    float na_pool = fmaxf(sqrtf(poolN), 1e-6f);
    float nb_pool = fmaxf(pBc * sqrtf(sb), 1e-6f);
    float poolc = -(pBc * poolDot) / (na_pool * nb_pool) * 0.5f * (pAc + pBc);

    // flow (image t; block t=6 also handles image 7)
    float mx = pAc;
#pragma unroll
    for (int k = 0; k < 9; k++)
        if (k != 4 && ((inbM >> k) & 1u)) mx = fmaxf(mx, pA[nbc[k]]);
    float f = flow[(size_t)(t * BB + b) * GG + tid];
    float fsq = 0.f;
    if (f > 0.5f) { float d = mx - f; fsq = d * d; }
    float szp = pAc, sflow = f;
    if (t == 6) {
        float mxB = pBc;
#pragma unroll
        for (int k = 0; k < 9; k++)
            if (k != 4 && ((inbM >> k) & 1u)) mxB = fmaxf(mxB, pB[nbc[k]]);
        float f7 = flow[(size_t)(7 * BB + b) * GG + tid];
        if (f7 > 0.5f) { float d = mxB - f7; fsq += d * d; }
        szp += pBc;
        sflow += f7;
    }

    // pres triple (t, t+1, t+2) for t <= 5
    float pres = 0.f;
    if (t <= 5) {
        float pC = zp[(size_t)((t + 2) * BB + b) * GG + tid];
        float s02 = pC - pAc;
        float sim = 1.f - s02 * s02;
        float d2 = pC - pBc, d0 = pAc - pBc;
        pres = sim * (d2 * d2 + d0 * d0);
    }

    // ---- block reduce 7 scalars -> private partial slot (no contended atomics) ----
    float r[7] = {zdiff, pres, poolc, obj, fsq, szp, sflow};
    int w = tid >> 6;
#pragma unroll
    for (int j = 0; j < 7; j++) {
        float rv = wred(r[j]);
        if (lane == 0) bred[j][w] = rv;
    }
    __syncthreads();
    if (tid < 7)
        part[pairIdx * 8 + tid] = bred[tid][0] + bred[tid][1] + bred[tid][2] + bred[tid][3];

    // ---- last-block-done final reduction (threadfence reduction pattern) ----
    __threadfence();                 // release partials (device scope)
    if (tid == 0) {
        unsigned old = atomicAdd((unsigned*)wsbase, 1u);
        isLast = (old == (unsigned)(NPAIR - 1));
    }
    __syncthreads();
    if (!isLast) return;
    __threadfence();                 // acquire side

    float cacc[7] = {0.f, 0.f, 0.f, 0.f, 0.f, 0.f, 0.f};
    for (int p = tid; p < NPAIR; p += 256) {
        const float* rr = part + p * 8;
#pragma unroll
        for (int j = 0; j < 7; j++) cacc[j] += rr[j];
    }
#pragma unroll
    for (int j = 0; j < 7; j++) {
        float rv = wred(cacc[j]);
        if (lane == 0) bred[j][w] = rv;
    }
    __syncthreads();
    if (tid == 0) {
        float s[7];
#pragma unroll
        for (int j = 0; j < 7; j++) s[j] = bred[j][0] + bred[j][1] + bred[j][2] + bred[j][3];
        float step = (float)gs[0];
        float scale_obj = fminf(1.f, step / 200000.f);
        float scale_flow = fmaxf(0.f, 1.f - step / 100000.f);
        float flow_loss = s[4] + 100.f * fmaxf(0.f, s[5] - s[6]);
        out[0] = s[0]                       // z_what_loss * ADJ_W
               + s[1]                       // z_pres_loss * PRES_W
               + s[2]                       // pool (already negated) * POOL_W
               + s[3] * scale_obj * 10.0f   // objects * OBJ_W
               + flow_loss * scale_flow;    // FLOW_W = 1
    }
}

extern "C" void kernel_launch(void* const* d_in, const int* in_sizes, int n_in,
                              void* d_out, int out_size, void* d_ws, size_t ws_size,
                              hipStream_t stream) {
    const float* zw = (const float*)d_in[0];
    const float* zp = (const float*)d_in[1];
    const float* fl = (const float*)d_in[2];
    const int* gs = (const int*)d_in[3];
    float* ws = (float*)d_ws;

    hipMemsetAsync(d_ws, 0, 64, stream);   // zero the done-counter line
    pair_kernel<<<NPAIR, 256, 0, stream>>>(zw, zp, fl, ws, gs, (float*)d_out);
}

// Round 5
// 196.539 us; speedup vs baseline: 1.5762x; 1.5762x over previous
//
#include <hip/hip_runtime.h>
#include <math.h>

// Problem constants
#define TT 8
#define BB 128
#define GG 256
#define DD 64
#define NCH 8     // D chunks (8 floats each)
#define CF4 2     // float4s per cell per chunk
#define ST 3      // LDS stride in float4s (12 dwords: 12k%32 covers all 8 bank
                  // groups with period 8 -> conflict-free, same property as ST=5)
#define NPAIR ((TT - 1) * BB)

// ws layout: [0..15] floats reserved (u32 done-counter at [0], memset to 0)
//            partials at ws+16: part[pair*8 + j], j: 0 zdiff, 1 pres, 2 poolc(neg),
//            3 obj, 4 flow_sq, 5 sum(zp), 6 sum(flow)

__device__ inline float wred(float v) {
#pragma unroll
    for (int off = 32; off > 0; off >>= 1) v += __shfl_xor(v, off, 64);
    return v;
}
__device__ inline float dot4(float4 a, float4 b) {
    return a.x * b.x + a.y * b.y + a.z * b.z + a.w * b.w;
}
__device__ inline float4 fabs4(float4 a) {
    return make_float4(fabsf(a.x), fabsf(a.y), fabsf(a.z), fabsf(a.w));
}
__device__ inline float4 max4(float4 a, float4 b) {
    return make_float4(fmaxf(a.x, b.x), fmaxf(a.y, b.y), fmaxf(a.z, b.z), fmaxf(a.w, b.w));
}
__device__ inline float4 scale4(float4 a, float s) {
    return make_float4(a.x * s, a.y * s, a.z * s, a.w * s);
}
__device__ inline float4 sub4(float4 a, float4 b) {
    return make_float4(a.x - b.x, a.y - b.y, a.z - b.z, a.w - b.w);
}
__device__ inline float4 shfl4(float4 v, int src) {
    return make_float4(__shfl(v.x, src, 64), __shfl(v.y, src, 64),
                       __shfl(v.z, src, 64), __shfl(v.w, src, 64));
}

// NOTE: no min-waves arg — __launch_bounds__(256,4) made the allocator pick
// VGPR=64 and spill 293 MB of scratch (round-4 post-mortem).
__global__ __launch_bounds__(256) void pair_kernel(const float* __restrict__ zw,
                                                   const float* __restrict__ zp,
                                                   const float* __restrict__ flow,
                                                   float* __restrict__ wsbase,
                                                   const int* __restrict__ gs,
                                                   float* __restrict__ out) {
    const int pairIdx = blockIdx.x;            // 0 .. 7*BB-1
    const int t = pairIdx >> 7;                // BB = 128
    const int b = pairIdx & (BB - 1);
    const int tid = threadIdx.x;
    const int gi = tid >> 4, gj = tid & 15;
    const int lane = tid & 63;

    __shared__ float4 shR[GG * ST];            // row-max of wa (pool intermediate)
    __shared__ float4 shB[GG * ST];            // raw B chunk
    __shared__ float pA[GG], pB[GG], nB[GG];
    __shared__ float bred[8][4];
    __shared__ int isLast;

    float* part = wsbase + 16;

    const float4* gA = (const float4*)zw + (size_t)(t * BB + b) * 1024;
    const float4* gB = gA + (size_t)BB * 1024;

    const float pAc = zp[(size_t)(t * BB + b) * GG + tid];
    const float pBc = zp[(size_t)((t + 1) * BB + b) * GG + tid];
    pA[tid] = pAc;
    pB[tid] = pBc;

    // 9 wrapped neighbors (jnp.roll semantics) + in-bounds bitmask (clamped ops)
    int nbc[9];
    unsigned inbM = 0;
    {
        int m = 0;
#pragma unroll
        for (int di = -1; di <= 1; di++) {
#pragma unroll
            for (int dj = -1; dj <= 1; dj++) {
                nbc[m] = (((gi + di) & 15) << 4) | ((gj + dj) & 15);
                if (((unsigned)(gi + di) < 16u) && ((unsigned)(gj + dj) < 16u))
                    inbM |= (1u << m);
                m++;
            }
        }
    }
    __syncthreads();

    float zdiff = 0.f, sa = 0.f, sb = 0.f, poolDot = 0.f, poolN = 0.f;
    float dots[9] = {0.f, 0.f, 0.f, 0.f, 0.f, 0.f, 0.f, 0.f, 0.f};

    // unroll 1: full unroll hoists all chunks' global loads and spills
    // (round-2 post-mortem: VGPR=256, 293 MB scratch traffic)
#pragma unroll 1
    for (int c = 0; c < NCH; c++) {
        float4 aA[CF4], aB[CF4];
#pragma unroll
        for (int q = 0; q < CF4; q++) {
            aA[q] = gA[tid * 16 + c * CF4 + q];
            aB[q] = gB[tid * 16 + c * CF4 + q];
        }
        // register-local terms + row-max via intra-wave shuffle (gj+-1 never
        // crosses the 64-lane wave: rows of 16, clamped at row edges)
#pragma unroll
        for (int q = 0; q < CF4; q++) {
            float4 d = sub4(aB[q], aA[q]);
            zdiff += dot4(d, d);
            sa += dot4(aA[q], aA[q]);
            sb += dot4(aB[q], aB[q]);
            dots[4] += dot4(aA[q], aB[q]);          // center dot from registers
            float4 wa = scale4(fabs4(aA[q]), pAc);
            float4 rm = wa;
            float4 lft = shfl4(wa, lane - 1);
            if (gj > 0) rm = max4(rm, lft);
            float4 rgt = shfl4(wa, lane + 1);
            if (gj < 15) rm = max4(rm, rgt);
            shB[tid * ST + q] = aB[q];
            shR[tid * ST + q] = rm;
        }
        __syncthreads();

        // neighbor dots: A(center, regs) . B(neighbor, LDS)
#pragma unroll
        for (int k = 0; k < 9; k++) {
            if (k == 4) continue;
            int base = nbc[k] * ST;
#pragma unroll
            for (int q = 0; q < CF4; q++) dots[k] += dot4(aA[q], shB[base + q]);
        }

        // pool: clamped col-max of row-max, then accumulate dot/norm
#pragma unroll
        for (int q = 0; q < CF4; q++) {
            float4 sm = shR[tid * ST + q];
            if (gi > 0) sm = max4(sm, shR[(tid - 16) * ST + q]);
            if (gi < 15) sm = max4(sm, shR[(tid + 16) * ST + q]);
            poolDot += dot4(sm, fabs4(aB[q]));
            poolN += dot4(sm, sm);
        }
        __syncthreads();   // before next chunk overwrites shR/shB
    }

    // ---- epilogues ----
    nB[tid] = sqrtf(sb);
    __syncthreads();

    // objects
    float prior_n = fmaxf(sqrtf(sa), 1e-8f);
    float sum_sim = 0.f, max_sim = -1e30f;
    bool has = false;
#pragma unroll
    for (int k = 0; k < 9; k++) {
        float nn = fmaxf(nB[nbc[k]], 1e-8f);
        float s = dots[k] / (prior_n * nn);
        if (pB[nbc[k]] > 0.5f) {
            sum_sim += s;
            max_sim = fmaxf(max_sim, s);
            has = true;
        }
    }
    float obj = ((pAc > 0.5f) && has) ? (sum_sim - 5.0f * max_sim) : 0.f;

    // pool
    float na_pool = fmaxf(sqrtf(poolN), 1e-6f);
    float nb_pool = fmaxf(pBc * sqrtf(sb), 1e-6f);
    float poolc = -(pBc * poolDot) / (na_pool * nb_pool) * 0.5f * (pAc + pBc);

    // flow (image t; block t=6 also handles image 7)
    float mx = pAc;
#pragma unroll
    for (int k = 0; k < 9; k++)
        if (k != 4 && ((inbM >> k) & 1u)) mx = fmaxf(mx, pA[nbc[k]]);
    float f = flow[(size_t)(t * BB + b) * GG + tid];
    float fsq = 0.f;
    if (f > 0.5f) { float d = mx - f; fsq = d * d; }
    float szp = pAc, sflow = f;
    if (t == 6) {
        float mxB = pBc;
#pragma unroll
        for (int k = 0; k < 9; k++)
            if (k != 4 && ((inbM >> k) & 1u)) mxB = fmaxf(mxB, pB[nbc[k]]);
        float f7 = flow[(size_t)(7 * BB + b) * GG + tid];
        if (f7 > 0.5f) { float d = mxB - f7; fsq += d * d; }
        szp += pBc;
        sflow += f7;
    }

    // pres triple (t, t+1, t+2) for t <= 5
    float pres = 0.f;
    if (t <= 5) {
        float pC = zp[(size_t)((t + 2) * BB + b) * GG + tid];
        float s02 = pC - pAc;
        float sim = 1.f - s02 * s02;
        float d2 = pC - pBc, d0 = pAc - pBc;
        pres = sim * (d2 * d2 + d0 * d0);
    }

    // ---- block reduce 7 scalars -> private partial slot (no contended atomics) ----
    float r[7] = {zdiff, pres, poolc, obj, fsq, szp, sflow};
    int w = tid >> 6;
#pragma unroll
    for (int j = 0; j < 7; j++) {
        float rv = wred(r[j]);
        if (lane == 0) bred[j][w] = rv;
    }
    __syncthreads();
    if (tid < 7)
        part[pairIdx * 8 + tid] = bred[tid][0] + bred[tid][1] + bred[tid][2] + bred[tid][3];

    // ---- last-block-done final reduction (threadfence reduction pattern) ----
    __threadfence();                 // release partials (device scope)
    if (tid == 0) {
        unsigned old = atomicAdd((unsigned*)wsbase, 1u);
        isLast = (old == (unsigned)(NPAIR - 1));
    }
    __syncthreads();
    if (!isLast) return;
    __threadfence();                 // acquire side

    float cacc[7] = {0.f, 0.f, 0.f, 0.f, 0.f, 0.f, 0.f};
    for (int p = tid; p < NPAIR; p += 256) {
        const float* rr = part + p * 8;
#pragma unroll
        for (int j = 0; j < 7; j++) cacc[j] += rr[j];
    }
#pragma unroll
    for (int j = 0; j < 7; j++) {
        float rv = wred(cacc[j]);
        if (lane == 0) bred[j][w] = rv;
    }
    __syncthreads();
    if (tid == 0) {
        float s[7];
#pragma unroll
        for (int j = 0; j < 7; j++) s[j] = bred[j][0] + bred[j][1] + bred[j][2] + bred[j][3];
        float step = (float)gs[0];
        float scale_obj = fminf(1.f, step / 200000.f);
        float scale_flow = fmaxf(0.f, 1.f - step / 100000.f);
        float flow_loss = s[4] + 100.f * fmaxf(0.f, s[5] - s[6]);
        out[0] = s[0]                       // z_what_loss * ADJ_W
               + s[1]                       // z_pres_loss * PRES_W
               + s[2]                       // pool (already negated) * POOL_W
               + s[3] * scale_obj * 10.0f   // objects * OBJ_W
               + flow_loss * scale_flow;    // FLOW_W = 1
    }
}

extern "C" void kernel_launch(void* const* d_in, const int* in_sizes, int n_in,
                              void* d_out, int out_size, void* d_ws, size_t ws_size,
                              hipStream_t stream) {
    const float* zw = (const float*)d_in[0];
    const float* zp = (const float*)d_in[1];
    const float* fl = (const float*)d_in[2];
    const int* gs = (const int*)d_in[3];
    float* ws = (float*)d_ws;

    hipMemsetAsync(d_ws, 0, 64, stream);   // zero the done-counter line
    pair_kernel<<<NPAIR, 256, 0, stream>>>(zw, zp, fl, ws, gs, (float*)d_out);
}

// Round 6
// 132.190 us; speedup vs baseline: 2.3434x; 1.4868x over previous
//
#include <hip/hip_runtime.h>
#include <math.h>

// Problem constants
#define TT 8
#define BB 128
#define GG 256
#define DD 64
#define NCH 4     // D chunks (16 floats each): one 64B line per thread per array
                  // per chunk, fully consumed in-phase (round-5 post-mortem:
                  // CF4=2 split lines across phases -> L1 thrash, 2.7x slower)
#define CF4 4     // float4s per cell per chunk
#define ST 5      // LDS stride in float4s (20 dwords, period-8 full bank coverage;
                  // ST=4 was 8-way conflict: 1.02e7 SQ_LDS_BANK_CONFLICT, round 4)
#define NPAIR ((TT - 1) * BB)

// ws layout: part[pair*8 + j], j: 0 zdiff, 1 pres, 2 poolc(neg), 3 obj,
//                                 4 flow_sq, 5 sum(zp), 6 sum(flow)

__device__ inline float wred(float v) {
#pragma unroll
    for (int off = 32; off > 0; off >>= 1) v += __shfl_xor(v, off, 64);
    return v;
}
__device__ inline float dot4(float4 a, float4 b) {
    return a.x * b.x + a.y * b.y + a.z * b.z + a.w * b.w;
}
__device__ inline float4 fabs4(float4 a) {
    return make_float4(fabsf(a.x), fabsf(a.y), fabsf(a.z), fabsf(a.w));
}
__device__ inline float4 max4(float4 a, float4 b) {
    return make_float4(fmaxf(a.x, b.x), fmaxf(a.y, b.y), fmaxf(a.z, b.z), fmaxf(a.w, b.w));
}
__device__ inline float4 scale4(float4 a, float s) {
    return make_float4(a.x * s, a.y * s, a.z * s, a.w * s);
}
__device__ inline float4 sub4(float4 a, float4 b) {
    return make_float4(a.x - b.x, a.y - b.y, a.z - b.z, a.w - b.w);
}
__device__ inline float4 shfl4(float4 v, int src) {
    return make_float4(__shfl(v.x, src, 64), __shfl(v.y, src, 64),
                       __shfl(v.z, src, 64), __shfl(v.w, src, 64));
}

// NOTE: no min-waves arg — __launch_bounds__(256,4) made the allocator pick
// VGPR=64 and spill 293 MB of scratch (round-4 post-mortem).
__global__ __launch_bounds__(256) void pair_kernel(const float* __restrict__ zw,
                                                   const float* __restrict__ zp,
                                                   const float* __restrict__ flow,
                                                   float* __restrict__ part) {
    const int pairIdx = blockIdx.x;            // 0 .. 7*BB-1
    const int t = pairIdx >> 7;                // BB = 128
    const int b = pairIdx & (BB - 1);
    const int tid = threadIdx.x;
    const int gi = tid >> 4, gj = tid & 15;
    const int lane = tid & 63;

    __shared__ float4 shS[GG * ST];            // single staging buffer: B chunk,
                                               // then row-max (overwritten per phase)
    __shared__ float pA[GG], pB[GG], nB[GG];
    __shared__ float bred[8][4];

    const float4* gA = (const float4*)zw + (size_t)(t * BB + b) * 1024;
    const float4* gB = gA + (size_t)BB * 1024;

    const float pAc = zp[(size_t)(t * BB + b) * GG + tid];
    const float pBc = zp[(size_t)((t + 1) * BB + b) * GG + tid];
    pA[tid] = pAc;
    pB[tid] = pBc;

    // 9 wrapped neighbors (jnp.roll semantics) + in-bounds bitmask (clamped ops)
    int nbc[9];
    unsigned inbM = 0;
    {
        int m = 0;
#pragma unroll
        for (int di = -1; di <= 1; di++) {
#pragma unroll
            for (int dj = -1; dj <= 1; dj++) {
                nbc[m] = (((gi + di) & 15) << 4) | ((gj + dj) & 15);
                if (((unsigned)(gi + di) < 16u) && ((unsigned)(gj + dj) < 16u))
                    inbM |= (1u << m);
                m++;
            }
        }
    }
    __syncthreads();

    float zdiff = 0.f, sa = 0.f, sb = 0.f, poolDot = 0.f, poolN = 0.f;
    float dots[9] = {0.f, 0.f, 0.f, 0.f, 0.f, 0.f, 0.f, 0.f, 0.f};

    // unroll 1: full unroll hoists all chunks' global loads and spills
    // (round-2 post-mortem: VGPR=256, 293 MB scratch traffic)
#pragma unroll 1
    for (int c = 0; c < NCH; c++) {
        float4 aA[CF4], aB[CF4], rm[CF4];
#pragma unroll
        for (int q = 0; q < CF4; q++) {
            aA[q] = gA[tid * 16 + c * CF4 + q];
            aB[q] = gB[tid * 16 + c * CF4 + q];
        }
        // register-local terms + row-max via intra-wave shuffle (gj+-1 never
        // crosses the 64-lane wave: rows of 16, clamped at row edges)
#pragma unroll
        for (int q = 0; q < CF4; q++) {
            float4 d = sub4(aB[q], aA[q]);
            zdiff += dot4(d, d);
            sa += dot4(aA[q], aA[q]);
            sb += dot4(aB[q], aB[q]);
            dots[4] += dot4(aA[q], aB[q]);          // center dot from registers
            float4 wa = scale4(fabs4(aA[q]), pAc);
            rm[q] = wa;
            float4 lft = shfl4(wa, lane - 1);
            if (gj > 0) rm[q] = max4(rm[q], lft);
            float4 rgt = shfl4(wa, lane + 1);
            if (gj < 15) rm[q] = max4(rm[q], rgt);
            shS[tid * ST + q] = aB[q];              // stage B
        }
        __syncthreads();

        // neighbor dots: A(center, regs) . B(neighbor, LDS)
#pragma unroll
        for (int k = 0; k < 9; k++) {
            if (k == 4) continue;
            int base = nbc[k] * ST;
#pragma unroll
            for (int q = 0; q < CF4; q++) dots[k] += dot4(aA[q], shS[base + q]);
        }
        __syncthreads();   // all B reads done; safe to overwrite with row-max

#pragma unroll
        for (int q = 0; q < CF4; q++) shS[tid * ST + q] = rm[q];
        __syncthreads();

        // pool: clamped col-max of row-max (own value from regs), dot/norm accum
#pragma unroll
        for (int q = 0; q < CF4; q++) {
            float4 sm = rm[q];
            if (gi > 0) sm = max4(sm, shS[(tid - 16) * ST + q]);
            if (gi < 15) sm = max4(sm, shS[(tid + 16) * ST + q]);
            poolDot += dot4(sm, fabs4(aB[q]));
            poolN += dot4(sm, sm);
        }
        __syncthreads();   // before next chunk re-stages shS
    }

    // ---- epilogues ----
    nB[tid] = sqrtf(sb);
    __syncthreads();

    // objects
    float prior_n = fmaxf(sqrtf(sa), 1e-8f);
    float sum_sim = 0.f, max_sim = -1e30f;
    bool has = false;
#pragma unroll
    for (int k = 0; k < 9; k++) {
        float nn = fmaxf(nB[nbc[k]], 1e-8f);
        float s = dots[k] / (prior_n * nn);
        if (pB[nbc[k]] > 0.5f) {
            sum_sim += s;
            max_sim = fmaxf(max_sim, s);
            has = true;
        }
    }
    float obj = ((pAc > 0.5f) && has) ? (sum_sim - 5.0f * max_sim) : 0.f;

    // pool
    float na_pool = fmaxf(sqrtf(poolN), 1e-6f);
    float nb_pool = fmaxf(pBc * sqrtf(sb), 1e-6f);
    float poolc = -(pBc * poolDot) / (na_pool * nb_pool) * 0.5f * (pAc + pBc);

    // flow (image t; block t=6 also handles image 7)
    float mx = pAc;
#pragma unroll
    for (int k = 0; k < 9; k++)
        if (k != 4 && ((inbM >> k) & 1u)) mx = fmaxf(mx, pA[nbc[k]]);
    float f = flow[(size_t)(t * BB + b) * GG + tid];
    float fsq = 0.f;
    if (f > 0.5f) { float d = mx - f; fsq = d * d; }
    float szp = pAc, sflow = f;
    if (t == 6) {
        float mxB = pBc;
#pragma unroll
        for (int k = 0; k < 9; k++)
            if (k != 4 && ((inbM >> k) & 1u)) mxB = fmaxf(mxB, pB[nbc[k]]);
        float f7 = flow[(size_t)(7 * BB + b) * GG + tid];
        if (f7 > 0.5f) { float d = mxB - f7; fsq += d * d; }
        szp += pBc;
        sflow += f7;
    }

    // pres triple (t, t+1, t+2) for t <= 5
    float pres = 0.f;
    if (t <= 5) {
        float pC = zp[(size_t)((t + 2) * BB + b) * GG + tid];
        float s02 = pC - pAc;
        float sim = 1.f - s02 * s02;
        float d2 = pC - pBc, d0 = pAc - pBc;
        pres = sim * (d2 * d2 + d0 * d0);
    }

    // ---- block reduce 7 scalars -> private partial slot (no atomics/fences) ----
    float r[7] = {zdiff, pres, poolc, obj, fsq, szp, sflow};
    int w = tid >> 6;
#pragma unroll
    for (int j = 0; j < 7; j++) {
        float rv = wred(r[j]);
        if (lane == 0) bred[j][w] = rv;
    }
    __syncthreads();
    if (tid < 7)
        part[pairIdx * 8 + tid] = bred[tid][0] + bred[tid][1] + bred[tid][2] + bred[tid][3];
}

__global__ __launch_bounds__(256) void final_kernel(const float* __restrict__ part,
                                                    const int* __restrict__ gs,
                                                    float* __restrict__ out) {
    const int tid = threadIdx.x;
    __shared__ float bred[7][4];
    float c[7] = {0.f, 0.f, 0.f, 0.f, 0.f, 0.f, 0.f};
    for (int p = tid; p < NPAIR; p += 256) {
        const float* r = part + p * 8;
#pragma unroll
        for (int j = 0; j < 7; j++) c[j] += r[j];
    }
    int w = tid >> 6, lane = tid & 63;
#pragma unroll
    for (int j = 0; j < 7; j++) {
        float rv = wred(c[j]);
        if (lane == 0) bred[j][w] = rv;
    }
    __syncthreads();
    if (tid == 0) {
        float s[7];
#pragma unroll
        for (int j = 0; j < 7; j++) s[j] = bred[j][0] + bred[j][1] + bred[j][2] + bred[j][3];
        float step = (float)gs[0];
        float scale_obj = fminf(1.f, step / 200000.f);
        float scale_flow = fmaxf(0.f, 1.f - step / 100000.f);
        float flow_loss = s[4] + 100.f * fmaxf(0.f, s[5] - s[6]);
        out[0] = s[0]                       // z_what_loss * ADJ_W
               + s[1]                       // z_pres_loss * PRES_W
               + s[2]                       // pool (already negated) * POOL_W
               + s[3] * scale_obj * 10.0f   // objects * OBJ_W
               + flow_loss * scale_flow;    // FLOW_W = 1
    }
}

extern "C" void kernel_launch(void* const* d_in, const int* in_sizes, int n_in,
                              void* d_out, int out_size, void* d_ws, size_t ws_size,
                              hipStream_t stream) {
    const float* zw = (const float*)d_in[0];
    const float* zp = (const float*)d_in[1];
    const float* fl = (const float*)d_in[2];
    const int* gs = (const int*)d_in[3];
    float* ws = (float*)d_ws;

    pair_kernel<<<NPAIR, 256, 0, stream>>>(zw, zp, fl, ws);
    final_kernel<<<1, 256, 0, stream>>>(ws, gs, (float*)d_out);
}